// Round 13
// baseline (621.531 us; speedup 1.0000x reference)
//
#include <hip/hip_runtime.h>
#include <math.h>

#define B_   32
#define L_   2048
#define DSEQ 1024
#define DGLB 1024
#define H_   16
#define DK_  64
#define DV_  64
#define NT   32           // 64-row groups per (b,h) for partials
#define PSTRIDE 66        // m, s, y[64]

// Wc3 layout: [h][kt(16)][ks(2)][lhi(4)][col(128)][e(8)] bf16
// d = kt*64 + ks*32 + lhi*8 + e ; col<64 -> Wk col, col>=64 -> Wv col-64
// => per (h,kt,ks,lhi): 1024 elems contiguous; any 64-col chunk = 1 KB.

#define AS1 __attribute__((address_space(1)))
#define AS3 __attribute__((address_space(3)))

using u16    = unsigned short;
using bf16x8 = __attribute__((ext_vector_type(8))) short;
using f32x4  = __attribute__((ext_vector_type(4))) float;

__device__ __forceinline__ u16 f2bf(float x) {
  union { float f; unsigned int u; } v; v.f = x;
  return (u16)((v.u + 0x7fffu + ((v.u >> 16) & 1u)) >> 16);   // RNE
}

__device__ __forceinline__ float tanh_fast(float x) {
  float e = __builtin_exp2f(x * 2.885390081777927f);
  return 1.f - 2.f/(e + 1.f);
}

__device__ __forceinline__ float erf_fast(float x) {
  float ax = fabsf(x);
  float t  = 1.f/(1.f + 0.3275911f*ax);
  float p  = t*(0.254829592f + t*(-0.284496736f + t*(1.421413741f +
             t*(-1.453152027f + t*1.061405429f))));
  float e  = __builtin_exp2f(-ax*ax*1.4426950408889634f);
  float r  = 1.f - p*e;
  return copysignf(r, x);
}

#define PHASE_BARRIER(N)                                   \
  do {                                                     \
    __builtin_amdgcn_sched_barrier(0);                     \
    asm volatile("s_waitcnt vmcnt(" #N ")" ::: "memory");  \
    __builtin_amdgcn_s_barrier();                          \
    __builtin_amdgcn_sched_barrier(0);                     \
  } while (0)

// Wc3 pack; grid (H, 128 cols), 256 threads over d
__global__ void pack_w_kernel(const float* __restrict__ Wk,
                              const float* __restrict__ Wv,
                              u16* __restrict__ Wc) {
  const int h = blockIdx.x, j = blockIdx.y;
  const float* src = (j < DK_) ? (Wk + (size_t)h*DSEQ*DK_ + j)
                               : (Wv + (size_t)h*DSEQ*DV_ + (j - DK_));
  for (int d = threadIdx.x; d < DSEQ; d += blockDim.x) {
    int kt = d >> 6, ks = (d >> 5) & 1, lh = (d >> 3) & 3, e = d & 7;
    Wc[(size_t)(h*128 + kt*8 + ks*4 + lh)*1024 + j*8 + e] =
        f2bf(src[(size_t)d*64]);
  }
}

// S (fp32) -> Sb (bf16), flat
__global__ void s2bf_kernel(const float* __restrict__ S, u16* __restrict__ Sb) {
  const size_t G = (size_t)B_*L_*DSEQ/8;
  for (size_t i = (size_t)blockIdx.x*256 + threadIdx.x; i < G; i += (size_t)4096*256) {
    const float4* sp = (const float4*)(S + i*8);
    float4 v0 = sp[0], v1 = sp[1];
    bf16x8 wv;
    wv[0]=(short)f2bf(v0.x); wv[1]=(short)f2bf(v0.y);
    wv[2]=(short)f2bf(v0.z); wv[3]=(short)f2bf(v0.w);
    wv[4]=(short)f2bf(v1.x); wv[5]=(short)f2bf(v1.y);
    wv[6]=(short)f2bf(v1.z); wv[7]=(short)f2bf(v1.w);
    *(bf16x8*)(Sb + i*8) = wv;
  }
}

__global__ void q_proj_kernel(const float* __restrict__ X,
                              const float* __restrict__ Wq,
                              float* __restrict__ Q) {
  const int h = blockIdx.x, b0 = blockIdx.y*4, k = threadIdx.x;
  const float* w = Wq + (size_t)h*DGLB*DK_ + k;
  float a0=0.f, a1=0.f, a2=0.f, a3=0.f;
  for (int d = 0; d < DGLB; ++d) {
    float wv = w[(size_t)d*DK_];
    a0 += X[(size_t)(b0+0)*DGLB + d]*wv;
    a1 += X[(size_t)(b0+1)*DGLB + d]*wv;
    a2 += X[(size_t)(b0+2)*DGLB + d]*wv;
    a3 += X[(size_t)(b0+3)*DGLB + d]*wv;
  }
  Q[((size_t)(b0+0)*H_+h)*DK_+k] = tanhf(a0);
  Q[((size_t)(b0+1)*H_+h)*DK_+k] = tanhf(a1);
  Q[((size_t)(b0+2)*H_+h)*DK_+k] = tanhf(a2);
  Q[((size_t)(b0+3)*H_+h)*DK_+k] = tanhf(a3);
}

// grid 4096 = 512 M-tiles x 8 head-pairs. slot=id&7 -> XCD = head-pair
// (Wc3 slice 512 KB, L2-hot); Mtile diagonal-offset per XCD.
// Block: 128 rows x 256 cols (2 heads x (K64|V64)), 512 thr = 8 waves,
// wave (mw = w&1) x (nv = w>>1): 64x64 tile, acc[4][4].
// BOTH operands staged to LDS: 3 phase-buffers x (A 16K + B 32K), BK=64,
// 16 phases; stage(s+2) issue-early via global_load_lds (6 chunks/wave);
// counted PHASE_BARRIER(6) -> in-flight prefetch never drained.
// A rows 128 B, 8x16B slots, XOR swizzle slot^(row&7) (2 lanes/bank=free).
// B LDS [ks2][lhi4][col256][16B]: reads 256 B contiguous per llo-group.
template<int BF16SRC>
__global__ __launch_bounds__(512, 2) void fused_kernel(
    const float* __restrict__ S, const u16* __restrict__ Sb,
    const u16* __restrict__ Wc, const float* __restrict__ Q,
    float* __restrict__ part) {
  __shared__ u16   Slds[3*24576];    // 3 x 48 KB (A 8192 u16 + B 16384 u16)
  __shared__ float lpart[2][2][64];  // [mw][hp][row]

  const int id    = blockIdx.x;
  const int slot  = id & 7;                       // XCD = head-pair
  const int Mtile = ((id >> 3) + (slot << 6)) & 511;
  const int b     = Mtile >> 4;
  const int rowb  = (Mtile & 15) * 128;           // row base within b

  const int tid  = threadIdx.x;
  const int wave = tid >> 6, lane = tid & 63;
  const int lhi  = lane >> 4, llo = lane & 15;
  const int mw   = wave & 1,  nv  = wave >> 1;    // nv: 0..3
  const int hp   = nv >> 1,   isV = nv & 1;
  const int h    = slot*2 + hp;

  const u16* Sv = Sb + ((size_t)b*L_ + rowb)*DSEQ;
  const float* Sf = S + ((size_t)b*L_ + rowb)*DSEQ;
  const u16* Wh = Wc + (size_t)slot*2*131072;     // head-pair base (128K/head)

  // ---- stage phase `sub` into buffer p: 2 A-chunks + 4 B-chunks per wave
  auto stage_gl = [&](int sub, int p) {
    u16* Ab = Slds + p*24576;
    u16* Bb = Ab + 8192;
    // A: chunk j = rows 8j..8j+7 of [128 x 64k]; lane l -> row 8j+(l>>3),
    // phys slot q=l&7 holds logical slot g=q^(row&7) (src-side swizzle)
    #pragma unroll
    for (int it = 0; it < 2; ++it) {
      const int j   = wave*2 + it;
      const int row = 8*j + (lane >> 3);
      const int g   = (lane & 7) ^ (row & 7);
      const u16* gp = Sv + (size_t)row*DSEQ + sub*64 + g*8;
      __builtin_amdgcn_global_load_lds(
          (const AS1 void*)gp, (AS3 void*)(Ab + j*512), 16, 0, 0);
    }
    // B: chunk c: ks=c>>4, lh=(c>>2)&3, jg=c&3; col = jg*64+lane
    #pragma unroll
    for (int it = 0; it < 4; ++it) {
      const int c  = wave*4 + it;
      const int ks = c >> 4, lh = (c >> 2) & 3, jg = c & 3;
      const int col = jg*64 + lane;
      const u16* gp = Wh + (size_t)((col >> 7)*128 + sub*8 + ks*4 + lh)*1024
                         + (size_t)(col & 127)*8;
      __builtin_amdgcn_global_load_lds(
          (const AS1 void*)gp,
          (AS3 void*)(Bb + ((ks*4 + lh)*256 + jg*64)*8), 16, 0, 0);
    }
  };
  auto stage_reg = [&](int sub, int p) {          // fp32-S fallback
    u16* Ab = Slds + p*24576;
    u16* Bb = Ab + 8192;
    #pragma unroll
    for (int it = 0; it < 2; ++it) {
      const int j   = wave*2 + it;
      const int row = 8*j + (lane >> 3);
      const int g   = (lane & 7) ^ (row & 7);
      const float4* sp = (const float4*)(Sf + (size_t)row*DSEQ + sub*64 + g*8);
      float4 v0 = sp[0], v1 = sp[1];
      bf16x8 wv;
      wv[0]=(short)f2bf(v0.x); wv[1]=(short)f2bf(v0.y);
      wv[2]=(short)f2bf(v0.z); wv[3]=(short)f2bf(v0.w);
      wv[4]=(short)f2bf(v1.x); wv[5]=(short)f2bf(v1.y);
      wv[6]=(short)f2bf(v1.z); wv[7]=(short)f2bf(v1.w);
      *(bf16x8*)(Ab + j*512 + lane*8) = wv;
    }
    #pragma unroll
    for (int it = 0; it < 4; ++it) {
      const int c  = wave*4 + it;
      const int ks = c >> 4, lh = (c >> 2) & 3, jg = c & 3;
      const int col = jg*64 + lane;
      const u16* gp = Wh + (size_t)((col >> 7)*128 + sub*8 + ks*4 + lh)*1024
                         + (size_t)(col & 127)*8;
      bf16x8 wv = *(const bf16x8*)gp;
      *(bf16x8*)(Bb + ((ks*4 + lh)*256 + jg*64)*8 + lane*8) = wv;
    }
  };

  f32x4 acc[4][4];
  #pragma unroll
  for (int rt = 0; rt < 4; ++rt)
    #pragma unroll
    for (int c = 0; c < 4; ++c) acc[rt][c] = {0.f,0.f,0.f,0.f};

  // prologue
  if (BF16SRC) {
    stage_gl(0, 0);
    stage_gl(1, 1);
    PHASE_BARRIER(6);          // stage(0) complete; stage(1) in flight
  } else {
    stage_reg(0, 0);
    stage_reg(1, 1);
    __syncthreads();
  }

  const int arow0 = mw*64 + llo;        // + rt*16
  const int llo7  = llo & 7;

  int p = 0;                            // buffer of current phase
  for (int s = 0; s < 16; ++s) {
    const int pn = (p == 2) ? 0 : p + 1;        // stage target = p+2 mod 3
    const int p2 = (pn == 2) ? 0 : pn + 1;
    if (s < 14) {
      if (BF16SRC) { stage_gl(s + 2, p2); __builtin_amdgcn_sched_barrier(0); }
      else         { stage_reg(s + 2, p2); }
    }
    const u16* Ab = Slds + p*24576;
    const u16* Bb = Ab + 8192;
    #pragma unroll
    for (int kk = 0; kk < 2; ++kk) {
      const u16* Bp = Bb + ((kk*4 + lhi)*256 + nv*64 + llo)*8;
      bf16x8 b0 = *(const bf16x8*)(Bp);
      bf16x8 b1 = *(const bf16x8*)(Bp + 128);
      bf16x8 b2 = *(const bf16x8*)(Bp + 256);
      bf16x8 b3 = *(const bf16x8*)(Bp + 384);
      const int sl = ((kk*4 + lhi) ^ llo7)*8;
      __builtin_amdgcn_s_setprio(1);
      #pragma unroll
      for (int rt = 0; rt < 4; ++rt) {
        bf16x8 af = *(const bf16x8*)(Ab + (arow0 + rt*16)*64 + sl);
        acc[rt][0] = __builtin_amdgcn_mfma_f32_16x16x32_bf16(af, b0, acc[rt][0], 0,0,0);
        acc[rt][1] = __builtin_amdgcn_mfma_f32_16x16x32_bf16(af, b1, acc[rt][1], 0,0,0);
        acc[rt][2] = __builtin_amdgcn_mfma_f32_16x16x32_bf16(af, b2, acc[rt][2], 0,0,0);
        acc[rt][3] = __builtin_amdgcn_mfma_f32_16x16x32_bf16(af, b3, acc[rt][3], 0,0,0);
      }
      __builtin_amdgcn_s_setprio(0);
    }
    if (BF16SRC) {
      if (s < 14)       PHASE_BARRIER(6);   // stage(s+1) done, stage(s+2) flies
      else if (s == 14) PHASE_BARRIER(0);
    } else {
      __syncthreads();
    }
    p = pn;
  }

  // ---- epilogue: K-waves -> logits; V-waves -> gelu + weighted sums
  if (!isV) {
    const float* Qb = Q + ((size_t)b*H_ + h)*DK_;
    float q[4];
    #pragma unroll
    for (int c = 0; c < 4; ++c) q[c] = Qb[16*c + llo];
    #pragma unroll
    for (int rt = 0; rt < 4; ++rt) {
      #pragma unroll
      for (int r = 0; r < 4; ++r) {
        float pl = q[0]*tanh_fast(acc[rt][0][r]) + q[1]*tanh_fast(acc[rt][1][r])
                 + q[2]*tanh_fast(acc[rt][2][r]) + q[3]*tanh_fast(acc[rt][3][r]);
        pl += __shfl_xor(pl, 1); pl += __shfl_xor(pl, 2);
        pl += __shfl_xor(pl, 4); pl += __shfl_xor(pl, 8);
        if (llo == 0) lpart[mw][hp][rt*16 + lhi*4 + r] = pl;
      }
    }
  } else {
    #pragma unroll
    for (int rt = 0; rt < 4; ++rt)
      #pragma unroll
      for (int c = 0; c < 4; ++c)
        #pragma unroll
        for (int r = 0; r < 4; ++r) {
          float x = acc[rt][c][r];
          acc[rt][c][r] = 0.5f*x*(1.f + erf_fast(x*0.70710678118654752f));
        }
  }
  __syncthreads();

  if (isV) {
    float lg = lpart[mw][hp][lane] * 0.125f;   // 1/sqrt(64)
    float mx = lg;
    #pragma unroll
    for (int mk = 1; mk < 64; mk <<= 1) mx = fmaxf(mx, __shfl_xor(mx, mk));
    float ev = __expf(lg - mx);
    float sv = ev;
    #pragma unroll
    for (int mk = 1; mk < 64; mk <<= 1) sv += __shfl_xor(sv, mk);

    float er[16];
    #pragma unroll
    for (int rt = 0; rt < 4; ++rt)
      #pragma unroll
      for (int r = 0; r < 4; ++r)
        er[rt*4 + r] = __shfl(ev, rt*16 + lhi*4 + r);

    const int t_local = (Mtile & 15)*2 + mw;
    float* pt = part + (((size_t)b*H_ + h)*NT + t_local)*PSTRIDE;
    #pragma unroll
    for (int c = 0; c < 4; ++c) {
      float y = 0.f;
      #pragma unroll
      for (int rt = 0; rt < 4; ++rt)
        #pragma unroll
        for (int r = 0; r < 4; ++r)
          y += er[rt*4 + r]*acc[rt][c][r];
      y += __shfl_xor(y, 16); y += __shfl_xor(y, 32);
      if (lhi == 0) pt[2 + 16*c + llo] = y;
    }
    if (lane == 0) { pt[0] = mx; pt[1] = sv; }
  }
}

// merge NT tile-partials per (b,h); grid (H, B), block 64
__global__ void finalize_kernel(const float* __restrict__ part,
                                float* __restrict__ out) {
  const int h = blockIdx.x, b = blockIdx.y, v = threadIdx.x;
  const float* p = part + ((size_t)b*H_ + h)*(size_t)NT*PSTRIDE;
  float M = -3.0e38f;
  for (int tt = 0; tt < NT; ++tt) M = fmaxf(M, p[tt*PSTRIDE]);
  float ss = 0.f, y = 0.f;
  for (int tt = 0; tt < NT; ++tt) {
    float w = expf(p[tt*PSTRIDE] - M);
    ss += w*p[tt*PSTRIDE + 1];
    y  += w*p[tt*PSTRIDE + 2 + v];
  }
  out[((size_t)b*H_ + h)*DV_ + v] = y/ss;
}

extern "C" void kernel_launch(void* const* d_in, const int* in_sizes, int n_in,
                              void* d_out, int out_size, void* d_ws, size_t ws_size,
                              hipStream_t stream) {
  const float* X  = (const float*)d_in[0];
  const float* S  = (const float*)d_in[1];
  const float* Wq = (const float*)d_in[2];
  const float* Wk = (const float*)d_in[3];
  const float* Wv = (const float*)d_in[4];
  float* out = (float*)d_out;

  char* ws = (char*)d_ws;
  u16*   Wc    = (u16*)ws;                              // 4 MiB (Wc3 layout)
  float* Qbuf  = (float*)(ws + (4u<<20));               // 128 KiB
  float* part  = (float*)(ws + (4u<<20) + (128u<<10));  // ~4.3 MiB
  u16*   Sb    = (u16*)(ws + (16u<<20));                // 128 MiB (optional)
  const bool useBf = ws_size >= (144ull << 20);

  pack_w_kernel  <<<dim3(H_, 128),  256, 0, stream>>>(Wk, Wv, Wc);
  q_proj_kernel  <<<dim3(H_, B_/4),  64, 0, stream>>>(X, Wq, Qbuf);
  if (useBf) {
    s2bf_kernel       <<<dim3(4096), 256, 0, stream>>>(S, Sb);
    fused_kernel<1>   <<<dim3(4096), 512, 0, stream>>>(S, Sb, Wc, Qbuf, part);
  } else {
    fused_kernel<0>   <<<dim3(4096), 512, 0, stream>>>(S, Sb, Wc, Qbuf, part);
  }
  finalize_kernel<<<dim3(H_, B_),    64, 0, stream>>>(part, out);
}